// Round 1
// baseline (259.303 us; speedup 1.0000x reference)
//
#include <hip/hip_runtime.h>
#include <hip/hip_bf16.h>

#define Bb 256
#define Ss 2048
#define Tt 48
#define NCK 12           // chunks per batch (pws = 14.16 MB, round-3-proven size)
#define CLEN 171         // steps per chunk (last chunk: 166)

static constexpr float C_SHIFT = 4.875f;  // ~ln(48)+1: per-step growth ~= 1

typedef float f4   __attribute__((ext_vector_type(4)));
typedef short s4h  __attribute__((ext_vector_type(4)));
typedef __bf16 bf16x8 __attribute__((ext_vector_type(8)));

union U32x4 { unsigned u[4]; bf16x8 v; };
union U32x2 { unsigned u[2]; s4h v; };

__device__ __forceinline__ unsigned pk_trunc(float lo, float hi) {
    unsigned a = __builtin_bit_cast(unsigned, lo);
    unsigned b = __builtin_bit_cast(unsigned, hi);
#if __has_builtin(__builtin_amdgcn_perm)
    return __builtin_amdgcn_perm(b, a, 0x07060302u);
#else
    return (b & 0xFFFF0000u) | (a >> 16);
#endif
}
__device__ __forceinline__ unsigned pk_rne(float lo, float hi) {
    __hip_bfloat162 h = __float22bfloat162_rn(make_float2(lo, hi));
    union { __hip_bfloat16 b[2]; unsigned u; } t;
    t.b[0] = h.x; t.b[1] = h.y;
    return t.u;
}
__device__ __forceinline__ float bfu(unsigned u) { return __builtin_bit_cast(float, u); }

// k-slot bijection for the x32 operands: slot (g,j) holds k = sig(g,j).
__device__ __forceinline__ int sig32(int g, int j) {
    return 16 * (j >> 2) + 4 * g + (j & 3);
}

#define MFMA32(a,b,c) __builtin_amdgcn_mfma_f32_16x16x32_bf16(a, b, c, 0, 0, 0)
#define MFMA16(a,b,c) __builtin_amdgcn_mfma_f32_16x16x16bf16_1k(a, b, c, 0, 0, 0)

// ---------------------------------------------------------------------------
// One scan step: per n-tile, D = A32*B32 (K=32 rows 0..31) + A16*B16 (rows
// 32..47), rowscale by e, repack (natural row space throughout).
// ---------------------------------------------------------------------------
__device__ __forceinline__ void scan_step(const bf16x8 (&A32)[3], const s4h (&A16)[3],
                                          bf16x8 (&B32)[3], s4h (&B16)[3],
                                          const float* __restrict__ eb)
{
    f4 e0 = *(const f4*)(eb);          // e[4g + 0..3]      (rows of m-tile 0)
    f4 e1 = *(const f4*)(eb + 16);     // e[16 + 4g + 0..3] (m-tile 1)
    f4 e2 = *(const f4*)(eb + 32);     // e[32 + 4g + 0..3] (m-tile 2)
    const f4 z = {0.f, 0.f, 0.f, 0.f};
#pragma unroll
    for (int nt = 0; nt < 3; ++nt) {
        f4 c0v = MFMA32(A32[0], B32[nt], z);
        f4 c1v = MFMA32(A32[1], B32[nt], z);
        f4 c2v = MFMA32(A32[2], B32[nt], z);
        c0v = MFMA16(A16[0], B16[nt], c0v);
        c1v = MFMA16(A16[1], B16[nt], c1v);
        c2v = MFMA16(A16[2], B16[nt], c2v);
        U32x4 nb;
        nb.u[0] = pk_trunc(c0v[0] * e0[0], c0v[1] * e0[1]);
        nb.u[1] = pk_trunc(c0v[2] * e0[2], c0v[3] * e0[3]);
        nb.u[2] = pk_trunc(c1v[0] * e1[0], c1v[1] * e1[1]);
        nb.u[3] = pk_trunc(c1v[2] * e1[2], c1v[3] * e1[3]);
        B32[nt] = nb.v;
        U32x2 nc;
        nc.u[0] = pk_trunc(c2v[0] * e2[0], c2v[1] * e2[1]);
        nc.u[1] = pk_trunc(c2v[2] * e2[2], c2v[3] * e2[3]);
        B16[nt] = nc.v;
    }
}

// ---------------------------------------------------------------------------
// Phase 1: one wave per (batch, chunk): 48x48 transfer-matrix product in regs.
// NEW: also computes the gold trans+emit sum for its chunk (lanes 0..15, one
// step each per 16-step sub). The em gather hits L1 (same lines the wave just
// streamed for lex); tags/mask are loaded one sub ahead and the trn/em gathers
// are retired one sub later, so all gather latency hides under the MFMA block.
// Issue order per sub keeps the r[] prefetch NEWEST in the vmcnt queue, so no
// gold wait ever drains it.
// ---------------------------------------------------------------------------
__global__ __launch_bounds__(256, 3)
void crf_scan(const float* __restrict__ em, const int* __restrict__ tags,
              const int* __restrict__ mask, const float* __restrict__ trn,
              float* __restrict__ pws, float* __restrict__ out)
{
    __shared__ float lex[4][16 * Tt];          // per-wave 16-step exp(em) buffer
    const int tid = threadIdx.x, wv = tid >> 6, l = tid & 63;
    const int c0 = l & 15, g = l >> 4;
    const int wid = blockIdx.x * 4 + wv;
    const int b = wid / NCK, ck = wid % NCK;

    // A-frags
    bf16x8 A32[3]; s4h A16[3];
#pragma unroll
    for (int mt = 0; mt < 3; ++mt) {
        float v[8];
#pragma unroll
        for (int j = 0; j < 8; ++j)
            v[j] = __expf(trn[sig32(g, j) * Tt + 16 * mt + c0]);
        U32x4 a;
        a.u[0] = pk_rne(v[0], v[1]); a.u[1] = pk_rne(v[2], v[3]);
        a.u[2] = pk_rne(v[4], v[5]); a.u[3] = pk_rne(v[6], v[7]);
        A32[mt] = a.v;
        float w0 = __expf(trn[(32 + 4 * g + 0) * Tt + 16 * mt + c0]);
        float w1 = __expf(trn[(32 + 4 * g + 1) * Tt + 16 * mt + c0]);
        float w2 = __expf(trn[(32 + 4 * g + 2) * Tt + 16 * mt + c0]);
        float w3 = __expf(trn[(32 + 4 * g + 3) * Tt + 16 * mt + c0]);
        U32x2 c;
        c.u[0] = pk_rne(w0, w1); c.u[1] = pk_rne(w2, w3);
        A16[mt] = c.v;
    }

    // State init = identity
    bf16x8 B32[3]; s4h B16[3];
#pragma unroll
    for (int nt = 0; nt < 3; ++nt) {
        U32x4 bi;
#pragma unroll
        for (int q = 0; q < 4; ++q) {
            unsigned lo = (sig32(g, 2 * q)     == 16 * nt + c0) ? 0x3F80u : 0u;
            unsigned hi = (sig32(g, 2 * q + 1) == 16 * nt + c0) ? 0x3F80u : 0u;
            bi.u[q] = lo | (hi << 16);
        }
        B32[nt] = bi.v;
        U32x2 ci;
#pragma unroll
        for (int q = 0; q < 2; ++q) {
            unsigned lo = (nt == 2 && 4 * g + 2 * q     == c0) ? 0x3F80u : 0u;
            unsigned hi = (nt == 2 && 4 * g + 2 * q + 1 == c0) ? 0x3F80u : 0u;
            ci.u[q] = lo | (hi << 16);
        }
        B16[nt] = ci.v;
    }

    const int total = (ck == NCK - 1) ? (Ss - 1 - ck * CLEN) : CLEN;  // 171 / 166
    const int s0 = ck * CLEN + 1;
    const float* emb = em + (size_t)b * (Ss * Tt);
    const int* tgb = tags + (size_t)b * Ss;
    const int* mkb = mask + (size_t)b * Ss;
    float* lw = &lex[wv][0];
    const float* lexg = lw + g * 4;
    const long lim = (long)Ss * Tt - 4;

    // ---- gold pipeline state (lanes 0..15 active; others stay 0) ----
    float gold = 0.0f;
    float pend_trn = 0.0f, pend_em = 0.0f, pend_mf = 0.0f;
    int tp_cur = 0, tc_cur = 0, se_cur = 1; float mf_cur = 0.0f;
    int tp_nxt = 0, tc_nxt = 0, se_nxt = 1; float mf_nxt = 0.0f;
    if (l < 16) {                        // tags/mask for sub 0 (BEFORE r prefetch)
        int nst = (total < 16) ? total : 16;
        int ok = (l < nst);
        int se = ok ? (s0 + l) : (Ss - 1);
        tp_cur = tgb[se - 1];
        tc_cur = tgb[se];
        mf_cur = ok ? (float)mkb[se] : 0.0f;
        se_cur = se;
    }

    // prefetch sub 0 (early-issued global loads, consumed at loop top)
    f4 r[3];
#pragma unroll
    for (int i = 0; i < 3; ++i) {
        long o = (long)s0 * Tt + l * 4 + i * 256;
        if (o > lim) o = lim;
        r[i] = *(const f4*)(emb + o);
    }

    const int nsub = (total + 15) >> 4;
    for (int sub = 0; sub < nsub; ++sub) {
#pragma unroll
        for (int i = 0; i < 3; ++i)
#pragma unroll
            for (int j = 0; j < 4; ++j) r[i][j] = __expf(r[i][j] - C_SHIFT);
#pragma unroll
        for (int i = 0; i < 3; ++i) *(f4*)(lw + l * 4 + i * 256) = r[i];

        if (sub + 1 < nsub) {            // next sub's tags first, then em prefetch
            if (l < 16) {
                int base = (sub + 1) * 16;
                int nst = total - base; if (nst > 16) nst = 16;
                int ok = (l < nst);
                int se = ok ? (s0 + base + l) : (Ss - 1);
                tp_nxt = tgb[se - 1];
                tc_nxt = tgb[se];
                mf_nxt = ok ? (float)mkb[se] : 0.0f;
                se_nxt = se;
            }
#pragma unroll
            for (int i = 0; i < 3; ++i) {
                long o = (long)(s0 + (sub + 1) * 16) * Tt + l * 4 + i * 256;
                if (o > lim) o = lim;
                r[i] = *(const f4*)(emb + o);
            }
        }

        int nsteps = total - sub * 16;
        if (nsteps >= 16) {
#pragma unroll
            for (int u = 0; u < 16; ++u)
                scan_step(A32, A16, B32, B16, lexg + u * Tt);
        } else {
            for (int u = 0; u < nsteps; ++u)
                scan_step(A32, A16, B32, B16, lexg + u * Tt);
        }

        // retire previous sub's gold gathers (issued one full MFMA block ago);
        // then issue this sub's trn/em gathers (addresses from tags loaded last
        // iteration -> long retired; latency hides under next sub's MFMAs).
        gold += (pend_trn + pend_em) * pend_mf;
        if (l < 16) {
            pend_trn = trn[tp_cur * Tt + tc_cur];
            pend_em  = emb[(size_t)se_cur * Tt + tc_cur];
            pend_mf  = mf_cur;
            tp_cur = tp_nxt; tc_cur = tc_nxt; se_cur = se_nxt; mf_cur = mf_nxt;
        }
    }
    gold += (pend_trn + pend_em) * pend_mf;   // flush last sub
    gold += __shfl_xor(gold, 1);
    gold += __shfl_xor(gold, 2);
    gold += __shfl_xor(gold, 4);
    gold += __shfl_xor(gold, 8);
    if (l == 0) atomicAdd(out, gold * (-1.0f / 256.0f));

    // store 18 u32/lane, coalesced
    unsigned* pw = (unsigned*)pws + (size_t)wid * 1152 + l;
#pragma unroll
    for (int nt = 0; nt < 3; ++nt) {
        U32x4 a; a.v = B32[nt];
        U32x2 c; c.v = B16[nt];
        pw[(nt * 6 + 0) * 64] = a.u[0];
        pw[(nt * 6 + 1) * 64] = a.u[1];
        pw[(nt * 6 + 2) * 64] = a.u[2];
        pw[(nt * 6 + 3) * 64] = a.u[3];
        pw[(nt * 6 + 4) * 64] = c.u[0];
        pw[(nt * 6 + 5) * 64] = c.u[1];
    }
}

// ---------------------------------------------------------------------------
// Phase 2: one wave per batch; chain the 12 chunk matrices with renorm.
// Gold is gone (computed in crf_scan); only the 3 edge terms remain here.
// pws loads are double-buffered in registers (2-deep, named arrays, all
// compile-time indexed) so each chunk's loads hide under the previous chunk's
// shuffle-reduce chain.
// ---------------------------------------------------------------------------
__global__ __launch_bounds__(64)
void crf_finish(const float* __restrict__ em, const int* __restrict__ tags,
                const float* __restrict__ stt, const float* __restrict__ ent,
                const float* __restrict__ pws, float* __restrict__ out)
{
    __shared__ float alpha[Tt];
    const int b = blockIdx.x, l = threadIdx.x;
    const int c0 = l & 15, g = l >> 4;

    // edge gold terms (issue early; used only at the very end)
    const int* tg = tags + (size_t)b * Ss;
    int t0 = tg[0], tl = tg[Ss - 1];
    float edge = stt[t0] + em[(size_t)b * Ss * Tt + t0] + ent[tl];

    // alpha init (natural): alpha[i] = exp(stt[i] + em[b,0,i] - C)
    if (l < Tt) alpha[l] = __expf(stt[l] + em[(size_t)b * Ss * Tt + l] - C_SHIFT);

    const unsigned* pwb = (const unsigned*)pws + (size_t)b * NCK * 1152 + l;
    unsigned wA[18], wB[18];
#pragma unroll
    for (int q = 0; q < 18; ++q) wA[q] = pwb[q * 64];

    float acc = 0.0f;
#pragma unroll
    for (int ck = 0; ck < NCK; ++ck) {
        if (ck + 1 < NCK) {              // prefetch next chunk into the idle buffer
            const unsigned* pn = pwb + (size_t)(ck + 1) * 1152;
            if (ck & 1) {
#pragma unroll
                for (int q = 0; q < 18; ++q) wA[q] = pn[q * 64];
            } else {
#pragma unroll
                for (int q = 0; q < 18; ++q) wB[q] = pn[q * 64];
            }
        }
        float y[12];
#pragma unroll
        for (int i = 0; i < 12; ++i) y[i] = 0.0f;
#pragma unroll
        for (int nt = 0; nt < 3; ++nt) {
            float av = alpha[16 * nt + c0];
#pragma unroll
            for (int q = 0; q < 6; ++q) {
                unsigned wvv = (ck & 1) ? wB[nt * 6 + q] : wA[nt * 6 + q];  // ck const
                y[2 * q]     += bfu(wvv << 16)         * av;
                y[2 * q + 1] += bfu(wvv & 0xFFFF0000u) * av;
            }
        }
#pragma unroll
        for (int m = 1; m <= 8; m <<= 1)
#pragma unroll
            for (int i = 0; i < 12; ++i) y[i] += __shfl_xor(y[i], m);
        float mx = y[0];
#pragma unroll
        for (int i = 1; i < 12; ++i) mx = fmaxf(mx, y[i]);
        mx = fmaxf(mx, __shfl_xor(mx, 16));
        mx = fmaxf(mx, __shfl_xor(mx, 32));
        acc += __logf(mx);
        float rm = 1.0f / mx;
        if (c0 == 0) {
#pragma unroll
            for (int tt = 0; tt < 3; ++tt)
#pragma unroll
                for (int rr = 0; rr < 4; ++rr)
                    alpha[16 * tt + 4 * g + rr] = y[4 * tt + rr] * rm;
        }
    }
    // fwd = log(sum alpha * exp(ent)) + acc + S*C
    float part = (l < Tt) ? alpha[l] * __expf(ent[l]) : 0.0f;
#pragma unroll
    for (int m = 32; m >= 1; m >>= 1) part += __shfl_xor(part, m);
    if (l == 0) {
        float fwd = __logf(part) + acc + (float)Ss * C_SHIFT;
        atomicAdd(out, (fwd - edge) * (1.0f / 256.0f));
    }
}

// ---------------------------------------------------------------------------
extern "C" void kernel_launch(void* const* d_in, const int* in_sizes, int n_in,
                              void* d_out, int out_size, void* d_ws, size_t ws_size,
                              hipStream_t stream)
{
    const float* em  = (const float*)d_in[0];
    const int* tags  = (const int*)d_in[1];
    const int* mask  = (const int*)d_in[2];
    const float* trn = (const float*)d_in[3];
    const float* stt = (const float*)d_in[4];
    const float* ent = (const float*)d_in[5];
    float* out = (float*)d_out;
    float* pws = (float*)d_ws;   // 3072 waves x 1152 u32 = 14.16 MB (proven safe)

    hipMemsetAsync(d_out, 0, sizeof(float), stream);  // capturable memset node
    crf_scan<<<768, 256, 0, stream>>>(em, tags, mask, trn, pws, out);
    crf_finish<<<256, 64, 0, stream>>>(em, tags, stt, ent, pws, out);
}

// Round 2
// 249.102 us; speedup vs baseline: 1.0409x; 1.0409x over previous
//
#include <hip/hip_runtime.h>
#include <hip/hip_bf16.h>

#define Bb 256
#define Ss 2048
#define Tt 48
#define NCK 12           // chunks per batch (= waves per block)
#define CLEN 171         // steps per chunk (last chunk: 166)

static constexpr float C_SHIFT = 4.875f;  // ~ln(48)+1: per-step growth ~= 1

typedef float f4   __attribute__((ext_vector_type(4)));
typedef short s4h  __attribute__((ext_vector_type(4)));
typedef __bf16 bf16x8 __attribute__((ext_vector_type(8)));

union U32x4 { unsigned u[4]; bf16x8 v; };
union U32x2 { unsigned u[2]; s4h v; };

__device__ __forceinline__ unsigned pk_trunc(float lo, float hi) {
    unsigned a = __builtin_bit_cast(unsigned, lo);
    unsigned b = __builtin_bit_cast(unsigned, hi);
#if __has_builtin(__builtin_amdgcn_perm)
    return __builtin_amdgcn_perm(b, a, 0x07060302u);
#else
    return (b & 0xFFFF0000u) | (a >> 16);
#endif
}
__device__ __forceinline__ unsigned pk_rne(float lo, float hi) {
    __hip_bfloat162 h = __float22bfloat162_rn(make_float2(lo, hi));
    union { __hip_bfloat16 b[2]; unsigned u; } t;
    t.b[0] = h.x; t.b[1] = h.y;
    return t.u;
}
__device__ __forceinline__ float bfu(unsigned u) { return __builtin_bit_cast(float, u); }

// k-slot bijection for the x32 operands: slot (g,j) holds k = sig(g,j).
__device__ __forceinline__ int sig32(int g, int j) {
    return 16 * (j >> 2) + 4 * g + (j & 3);
}

#define MFMA32(a,b,c) __builtin_amdgcn_mfma_f32_16x16x32_bf16(a, b, c, 0, 0, 0)
#define MFMA16(a,b,c) __builtin_amdgcn_mfma_f32_16x16x16bf16_1k(a, b, c, 0, 0, 0)

// ---------------------------------------------------------------------------
// One scan step: per n-tile, D = A32*B32 (K=32 rows 0..31) + A16*B16 (rows
// 32..47), rowscale by e, repack (natural row space throughout).
// ---------------------------------------------------------------------------
__device__ __forceinline__ void scan_step(const bf16x8 (&A32)[3], const s4h (&A16)[3],
                                          bf16x8 (&B32)[3], s4h (&B16)[3],
                                          const float* __restrict__ eb)
{
    f4 e0 = *(const f4*)(eb);          // e[4g + 0..3]      (rows of m-tile 0)
    f4 e1 = *(const f4*)(eb + 16);     // e[16 + 4g + 0..3] (m-tile 1)
    f4 e2 = *(const f4*)(eb + 32);     // e[32 + 4g + 0..3] (m-tile 2)
    const f4 z = {0.f, 0.f, 0.f, 0.f};
#pragma unroll
    for (int nt = 0; nt < 3; ++nt) {
        f4 c0v = MFMA32(A32[0], B32[nt], z);
        f4 c1v = MFMA32(A32[1], B32[nt], z);
        f4 c2v = MFMA32(A32[2], B32[nt], z);
        c0v = MFMA16(A16[0], B16[nt], c0v);
        c1v = MFMA16(A16[1], B16[nt], c1v);
        c2v = MFMA16(A16[2], B16[nt], c2v);
        U32x4 nb;
        nb.u[0] = pk_trunc(c0v[0] * e0[0], c0v[1] * e0[1]);
        nb.u[1] = pk_trunc(c0v[2] * e0[2], c0v[3] * e0[3]);
        nb.u[2] = pk_trunc(c1v[0] * e1[0], c1v[1] * e1[1]);
        nb.u[3] = pk_trunc(c1v[2] * e1[2], c1v[3] * e1[3]);
        B32[nt] = nb.v;
        U32x2 nc;
        nc.u[0] = pk_trunc(c2v[0] * e2[0], c2v[1] * e2[1]);
        nc.u[1] = pk_trunc(c2v[2] * e2[2], c2v[3] * e2[3]);
        B16[nt] = nc.v;
    }
}

// ---------------------------------------------------------------------------
// Fused kernel: ONE block per batch (768 threads = 12 waves = 12 chunks).
//  - prologue: gold interior sum, distributed over all 768 threads (<=3
//    scattered gathers each; em is L3-resident). Tag loads issue first, the
//    A-frag exp build hides their latency, then the dependent trn/em gathers.
//  - scan: wave ck runs its 171-step chunk (round-0 structure, unchanged),
//    result (48x48 bf16-packed) stored to LDS -- no global pws round-trip.
//  - __syncthreads(); wave 0 chains the 12 chunk matrices from LDS with
//    renorm, combines with gold, one atomicAdd per block.
// LDS: lex 36864 + pwl 55296 + red 3072 + alpha 192 = 95424 B (1 block/CU,
// 12 waves/CU -- same wave parallelism as the old 768x4-wave layout).
// ---------------------------------------------------------------------------
__global__ __launch_bounds__(768, 3)
void crf_all(const float* __restrict__ em, const int* __restrict__ tags,
             const int* __restrict__ mask, const float* __restrict__ trn,
             const float* __restrict__ stt, const float* __restrict__ ent,
             float* __restrict__ out)
{
    __shared__ float lex[NCK][16 * Tt];      // per-wave 16-step exp(em) buffer
    __shared__ unsigned pwl[NCK][1152];      // per-chunk packed 48x48 result
    __shared__ float red[768];               // gold partials
    __shared__ float alpha[Tt];

    const int tid = threadIdx.x, wv = tid >> 6, l = tid & 63;
    const int c0 = l & 15, g = l >> 4;
    const int b = blockIdx.x, ck = wv;
    const float* emb = em + (size_t)b * (Ss * Tt);
    const int* tgb = tags + (size_t)b * Ss;
    const int* mkb = mask + (size_t)b * Ss;

    // ---- gold: tag/mask loads first (latency hidden by A-frag exp build) ----
    const int s1 = 1 + tid, s2 = s1 + 768, s3r = s2 + 768;
    const int ok3 = (s3r < Ss);
    const int s3 = ok3 ? s3r : (Ss - 1);
    int a1 = tgb[s1 - 1], b1 = tgb[s1];
    int a2 = tgb[s2 - 1], b2 = tgb[s2];
    int a3 = tgb[s3 - 1], b3 = tgb[s3];
    int m1i = mkb[s1], m2i = mkb[s2];
    int m3i = ok3 ? mkb[s3r] : 0;

    // ---- A-frags ----
    bf16x8 A32[3]; s4h A16[3];
#pragma unroll
    for (int mt = 0; mt < 3; ++mt) {
        float v[8];
#pragma unroll
        for (int j = 0; j < 8; ++j)
            v[j] = __expf(trn[sig32(g, j) * Tt + 16 * mt + c0]);
        U32x4 a;
        a.u[0] = pk_rne(v[0], v[1]); a.u[1] = pk_rne(v[2], v[3]);
        a.u[2] = pk_rne(v[4], v[5]); a.u[3] = pk_rne(v[6], v[7]);
        A32[mt] = a.v;
        float w0 = __expf(trn[(32 + 4 * g + 0) * Tt + 16 * mt + c0]);
        float w1 = __expf(trn[(32 + 4 * g + 1) * Tt + 16 * mt + c0]);
        float w2 = __expf(trn[(32 + 4 * g + 2) * Tt + 16 * mt + c0]);
        float w3 = __expf(trn[(32 + 4 * g + 3) * Tt + 16 * mt + c0]);
        U32x2 c;
        c.u[0] = pk_rne(w0, w1); c.u[1] = pk_rne(w2, w3);
        A16[mt] = c.v;
    }

    // ---- dependent gold gathers (addresses ready; consumed below) ----
    float g1t = trn[a1 * Tt + b1], g1e = emb[(size_t)s1 * Tt + b1];
    float g2t = trn[a2 * Tt + b2], g2e = emb[(size_t)s2 * Tt + b2];
    float g3t = trn[a3 * Tt + b3], g3e = emb[(size_t)s3 * Tt + b3];

    // ---- B identity init (VALU; hides gather latency) ----
    bf16x8 B32[3]; s4h B16[3];
#pragma unroll
    for (int nt = 0; nt < 3; ++nt) {
        U32x4 bi;
#pragma unroll
        for (int q = 0; q < 4; ++q) {
            unsigned lo = (sig32(g, 2 * q)     == 16 * nt + c0) ? 0x3F80u : 0u;
            unsigned hi = (sig32(g, 2 * q + 1) == 16 * nt + c0) ? 0x3F80u : 0u;
            bi.u[q] = lo | (hi << 16);
        }
        B32[nt] = bi.v;
        U32x2 ci;
#pragma unroll
        for (int q = 0; q < 2; ++q) {
            unsigned lo = (nt == 2 && 4 * g + 2 * q     == c0) ? 0x3F80u : 0u;
            unsigned hi = (nt == 2 && 4 * g + 2 * q + 1 == c0) ? 0x3F80u : 0u;
            ci.u[q] = lo | (hi << 16);
        }
        B16[nt] = ci.v;
    }

    red[tid] = (g1t + g1e) * (float)m1i + (g2t + g2e) * (float)m2i
             + (g3t + g3e) * (float)m3i;

    // ---- scan (round-0 structure) ----
    const int total = (ck == NCK - 1) ? (Ss - 1 - ck * CLEN) : CLEN;  // 171 / 166
    const int s0 = ck * CLEN + 1;
    float* lw = &lex[wv][0];
    const float* lexg = lw + g * 4;
    const long lim = (long)Ss * Tt - 4;

    // prefetch sub 0 (early-issued global loads, consumed at loop top)
    f4 r[3];
#pragma unroll
    for (int i = 0; i < 3; ++i) {
        long o = (long)s0 * Tt + l * 4 + i * 256;
        if (o > lim) o = lim;
        r[i] = *(const f4*)(emb + o);
    }

    const int nsub = (total + 15) >> 4;
    for (int sub = 0; sub < nsub; ++sub) {
#pragma unroll
        for (int i = 0; i < 3; ++i)
#pragma unroll
            for (int j = 0; j < 4; ++j) r[i][j] = __expf(r[i][j] - C_SHIFT);
#pragma unroll
        for (int i = 0; i < 3; ++i) *(f4*)(lw + l * 4 + i * 256) = r[i];

        if (sub + 1 < nsub) {        // issue next sub's loads before compute
#pragma unroll
            for (int i = 0; i < 3; ++i) {
                long o = (long)(s0 + (sub + 1) * 16) * Tt + l * 4 + i * 256;
                if (o > lim) o = lim;
                r[i] = *(const f4*)(emb + o);
            }
        }

        int nsteps = total - sub * 16;
        if (nsteps >= 16) {
#pragma unroll
            for (int u = 0; u < 16; ++u)
                scan_step(A32, A16, B32, B16, lexg + u * Tt);
        } else {
            for (int u = 0; u < nsteps; ++u)
                scan_step(A32, A16, B32, B16, lexg + u * Tt);
        }
    }

    // store 18 u32/lane into LDS (replaces global pws)
    unsigned* pw = &pwl[ck][0] + l;
#pragma unroll
    for (int nt = 0; nt < 3; ++nt) {
        U32x4 a; a.v = B32[nt];
        U32x2 c; c.v = B16[nt];
        pw[(nt * 6 + 0) * 64] = a.u[0];
        pw[(nt * 6 + 1) * 64] = a.u[1];
        pw[(nt * 6 + 2) * 64] = a.u[2];
        pw[(nt * 6 + 3) * 64] = a.u[3];
        pw[(nt * 6 + 4) * 64] = c.u[0];
        pw[(nt * 6 + 5) * 64] = c.u[1];
    }

    __syncthreads();

    // ---- wave 0: chain the 12 chunk matrices, combine with gold ----
    if (wv == 0) {
        int t0 = tgb[0], tl = tgb[Ss - 1];
        float edge = stt[t0] + emb[t0] + ent[tl];

        if (l < Tt) alpha[l] = __expf(stt[l] + emb[l] - C_SHIFT);

        float acc = 0.0f;
#pragma unroll
        for (int c = 0; c < NCK; ++c) {
            float y[12];
#pragma unroll
            for (int i = 0; i < 12; ++i) y[i] = 0.0f;
#pragma unroll
            for (int nt = 0; nt < 3; ++nt) {
                float av = alpha[16 * nt + c0];
#pragma unroll
                for (int q = 0; q < 6; ++q) {
                    unsigned w = pwl[c][(nt * 6 + q) * 64 + l];
                    y[2 * q]     += bfu(w << 16)         * av;
                    y[2 * q + 1] += bfu(w & 0xFFFF0000u) * av;
                }
            }
#pragma unroll
            for (int m = 1; m <= 8; m <<= 1)
#pragma unroll
                for (int i = 0; i < 12; ++i) y[i] += __shfl_xor(y[i], m);
            float mx = y[0];
#pragma unroll
            for (int i = 1; i < 12; ++i) mx = fmaxf(mx, y[i]);
            mx = fmaxf(mx, __shfl_xor(mx, 16));
            mx = fmaxf(mx, __shfl_xor(mx, 32));
            acc += __logf(mx);
            float rm = 1.0f / mx;
            if (c0 == 0) {
#pragma unroll
                for (int tt = 0; tt < 3; ++tt)
#pragma unroll
                    for (int rr = 0; rr < 4; ++rr)
                        alpha[16 * tt + 4 * g + rr] = y[4 * tt + rr] * rm;
            }
        }

        // gold total: 768 partials -> 12 per lane -> shuffle reduce
        float gs = 0.0f;
#pragma unroll
        for (int k = 0; k < 12; ++k) gs += red[l + 64 * k];
#pragma unroll
        for (int m = 32; m >= 1; m >>= 1) gs += __shfl_xor(gs, m);

        // fwd = log(sum alpha * exp(ent)) + acc + S*C
        float part = (l < Tt) ? alpha[l] * __expf(ent[l]) : 0.0f;
#pragma unroll
        for (int m = 32; m >= 1; m >>= 1) part += __shfl_xor(part, m);
        if (l == 0) {
            float fwd = __logf(part) + acc + (float)Ss * C_SHIFT;
            atomicAdd(out, (fwd - gs - edge) * (1.0f / 256.0f));
        }
    }
}

// ---------------------------------------------------------------------------
extern "C" void kernel_launch(void* const* d_in, const int* in_sizes, int n_in,
                              void* d_out, int out_size, void* d_ws, size_t ws_size,
                              hipStream_t stream)
{
    const float* em  = (const float*)d_in[0];
    const int* tags  = (const int*)d_in[1];
    const int* mask  = (const int*)d_in[2];
    const float* trn = (const float*)d_in[3];
    const float* stt = (const float*)d_in[4];
    const float* ent = (const float*)d_in[5];
    float* out = (float*)d_out;

    hipMemsetAsync(d_out, 0, sizeof(float), stream);  // capturable memset node
    crf_all<<<Bb, 768, 0, stream>>>(em, tags, mask, trn, stt, ent, out);
}